// Round 1
// baseline (611.520 us; speedup 1.0000x reference)
//
#include <hip/hip_runtime.h>

// Conv2DProduct: one-hot "sparse product" conv in log space.
// out[b,i,j,o] = x[b,2i,2j, o&31] + x[b,2i,2j+1, o>>5]
//             + x[b,2i+1,2j, 0]   + x[b,2i+1,2j+1, 0]
// Shapes: x [64,128,128,32] f32, out [64,64,64,512] f32.
// The one-hot kernel input (d_in[1]) is mathematically redundant — ignored.

constexpr int B     = 64;
constexpr int H     = 128;
constexpr int W     = 128;
constexpr int C_IN  = 32;
constexpr int HO    = 64;
constexpr int WO    = 64;
constexpr int C_OUT = 512;

constexpr int TOTAL4 = B * HO * WO * (C_OUT / 4);  // 33,554,432 float4 stores

__global__ __launch_bounds__(256) void conv2d_product_kernel(
    const float* __restrict__ x, float* __restrict__ out) {
    int t = blockIdx.x * blockDim.x + threadIdx.x;
    if (t >= TOTAL4) return;

    // Decompose flat float4 index (all power-of-2 dims -> shifts/masks only).
    int o4  = t & (C_OUT / 4 - 1);   // 0..127
    int pix = t >> 7;                // b*HO*WO + i*WO + j
    int j   = pix & (WO - 1);
    int bi  = pix >> 6;              // b*HO + i
    int i   = bi & (HO - 1);
    int b   = bi >> 6;

    int o = o4 << 2;                 // first of 4 consecutive output channels

    // Base of input pixel (2i, 2j) for batch b.
    const float* xbase = x + (((size_t)b * H + 2 * i) * W + 2 * j) * C_IN;

    // cell (0,0): 4 consecutive channels, 16B-aligned since (o&31) % 4 == 0
    const float4 a = *(const float4*)(xbase + (o & 31));
    // cell (0,1): same channel for all 4 outputs in this float4
    float bsum = xbase[C_IN + (o >> 5)];
    // cells (1,0) and (1,1): channel 0 of the next row (uniform per pixel)
    const float* xrow1 = xbase + (size_t)W * C_IN;
    float s = xrow1[0] + xrow1[C_IN];

    float add = bsum + s;
    float4 r;
    r.x = a.x + add;
    r.y = a.y + add;
    r.z = a.z + add;
    r.w = a.w + add;
    *(float4*)(out + (size_t)t * 4) = r;
}

extern "C" void kernel_launch(void* const* d_in, const int* in_sizes, int n_in,
                              void* d_out, int out_size, void* d_ws, size_t ws_size,
                              hipStream_t stream) {
    const float* x = (const float*)d_in[0];
    float* out = (float*)d_out;
    constexpr int BLOCK = 256;
    constexpr int GRID = (TOTAL4 + BLOCK - 1) / BLOCK;  // 131,072 blocks
    conv2d_product_kernel<<<GRID, BLOCK, 0, stream>>>(x, out);
}